// Round 1
// baseline (241.532 us; speedup 1.0000x reference)
//
#include <hip/hip_runtime.h>
#include <climits>
#include <cmath>

// DetectPeaks: xcorr [16,1,256,8192] f32 -> (neighbor_score, topk_scores, topk_index), each [rows,3]
// rows = 4096, W = 8192. One block (4 waves) per row, wave w owns elements [w*2048, w*2048+2048).
// Round-5 structure: NO LDS row staging. Direct global->register float4 stream with
// prefetch-1 software pipeline; quad halos via wave shuffles (left = shfl_up(cur.w),
// right = shfl_down(cur.x), cross-iteration carry via lane-63 broadcast). LDS reduced to
// 96 B merge scratch; __launch_bounds__(256,8) caps VGPR<=64 -> 8 blocks/CU (32 waves/CU).

#define PW    8192
#define PNLAG (PW / 2)
#define BLOCK 256
#define NW    4                 // waves per block
#define J     8                 // float4 quads per lane: wave span = J*64*4 = 2048 elems

__device__ __forceinline__ bool better(float av, int ai, float bv, int bi) {
  return (av > bv) || ((av == bv) && (ai < bi));   // lax.top_k: ties -> lower index
}

__device__ __forceinline__ void insert3_full(float v, int i,
                                             float &v0, int &i0,
                                             float &v1, int &i1,
                                             float &v2, int &i2) {
  if (better(v, i, v2, i2)) {
    if (better(v, i, v1, i1)) {
      if (better(v, i, v0, i0)) {
        v2 = v1; i2 = i1; v1 = v0; i1 = i0; v0 = v; i0 = i;
      } else {
        v2 = v1; i2 = i1; v1 = v; i1 = i;
      }
    } else {
      v2 = v; i2 = i;
    }
  }
}

// Exact float ties between distinct lags have ~0 probability; strict > suffices.
__device__ __forceinline__ void insert3_fast(float c, int ci,
                                             float &v0, int &i0,
                                             float &v1, int &i1,
                                             float &v2, int &i2) {
  const bool b2 = c > v2;
  const bool b1 = c > v1;
  const bool b0 = c > v0;
  v2 = b1 ? v1 : (b2 ? c : v2);  i2 = b1 ? i1 : (b2 ? ci : i2);
  v1 = b0 ? v0 : (b1 ? c : v1);  i1 = b0 ? i0 : (b1 ? ci : i1);
  v0 = b0 ? c  : v0;             i0 = b0 ? ci : i0;
}

__global__ __launch_bounds__(BLOCK, 8)
void detect_peaks_kernel(const float* __restrict__ x,
                         float* __restrict__ out,
                         int rows) {
  __shared__ float rv[NW * 3];   // per-wave top-3 values
  __shared__ int   ri[NW * 3];   // per-wave top-3 indices

  const int row  = blockIdx.x;
  const int t    = threadIdx.x;
  const int lane = t & 63;
  const int wave = t >> 6;
  const float* __restrict__ xr = x + (size_t)row * PW;

  const int span = J * 64 * 4;          // 2048 elements per wave
  const int base = wave * span;

  // Wave-edge halo elements (row edges pad -inf per torch max_pool2d semantics).
  // Wave-uniform addresses -> single coalesced request each.
  const float edgeL = (base > 0)         ? xr[base - 1]    : -INFINITY;
  const float edgeR = (base + span < PW) ? xr[base + span] : -INFINITY;

  float v0 = -INFINITY, v1 = -INFINITY, v2 = -INFINITY;
  int   i0 = INT_MAX,   i1 = INT_MAX,   i2 = INT_MAX;

  // prefetch-1 pipeline: cur holds iteration j's quad, nxt loads j+1 while j computes
  float4 cur = *(const float4*)(xr + base + lane * 4);
  float carry = edgeL;                  // element (p-1) for lane 0 of current iteration

#pragma unroll
  for (int j = 0; j < J; ++j) {
    float4 nxt = cur;
    if (j + 1 < J)
      nxt = *(const float4*)(xr + base + ((j + 1) * 64 + lane) * 4);

    // halos via shuffles: left = previous quad's .w, right = next quad's .x
    float left = __shfl_up(cur.w, 1);
    if (lane == 0) left = carry;
    const float nfirst = (j + 1 < J) ? __shfl(nxt.x, 0) : edgeR;  // next iter lane0 .x
    float right = __shfl_down(cur.x, 1);
    if (lane == 63) right = nfirst;
    carry = __shfl(cur.w, 63);          // this iter's last element -> next iter's lane0 left

    const int p = base + (j * 64 + lane) * 4;   // first element index of this quad

    // sliding 3-max over the 4 positions
    const float p01 = fmaxf(cur.x, cur.y);
    const float p12 = fmaxf(cur.y, cur.z);
    const float p23 = fmaxf(cur.z, cur.w);
    const float m0 = fmaxf(left, p01);
    const float m1 = fmaxf(p01, cur.z);
    const float m2 = fmaxf(p12, cur.w);
    const float m3 = fmaxf(p23, right);

    // NMS score: x where local max else 0
    const float s0 = (cur.x == m0) ? cur.x : 0.0f;
    const float s1 = (cur.y == m1) ? cur.y : 0.0f;
    const float s2 = (cur.z == m2) ? cur.z : 0.0f;
    const float s3 = (cur.w == m3) ? cur.w : 0.0f;

    // quad top-2 (left arg of >= always lower index => tie->lower-index preserved);
    // adjacent lags can't both be (distinct-valued) local maxima -> <=2 survivors per quad.
    const bool  a01 = s0 >= s1;
    const float hiA = a01 ? s0 : s1;   const int hiAi = a01 ? p     : p + 1;
    const float loA = a01 ? s1 : s0;   const int loAi = a01 ? p + 1 : p;
    const bool  a23 = s2 >= s3;
    const float hiB = a23 ? s2 : s3;   const int hiBi = a23 ? p + 2 : p + 3;
    const float loB = a23 ? s3 : s2;   const int loBi = a23 ? p + 3 : p + 2;

    const bool  ab  = hiA >= hiB;
    const float c1  = ab ? hiA : hiB;  const int c1i = ab ? hiAi : hiBi;
    const bool  sb  = ab ? (loA >= hiB) : (hiA >= loB);
    const float c2  = ab ? (sb ? loA : hiB) : (sb ? hiA : loB);
    const int   c2i = ab ? (sb ? loAi : hiBi) : (sb ? hiAi : loBi);

    insert3_fast(c1, c1i, v0, i0, v1, i1, v2, i2);
    insert3_fast(c2, c2i, v0, i0, v1, i1, v2, i2);

    cur = nxt;
  }

  // ---- wave-level tree merge (64 lanes) ----
#pragma unroll
  for (int off = 32; off > 0; off >>= 1) {
    float ov0 = __shfl_down(v0, off);
    int   oi0 = __shfl_down(i0, off);
    float ov1 = __shfl_down(v1, off);
    int   oi1 = __shfl_down(i1, off);
    float ov2 = __shfl_down(v2, off);
    int   oi2 = __shfl_down(i2, off);
    if (lane + off < 64) {
      insert3_full(ov0, oi0, v0, i0, v1, i1, v2, i2);
      insert3_full(ov1, oi1, v0, i0, v1, i1, v2, i2);
      insert3_full(ov2, oi2, v0, i0, v1, i1, v2, i2);
    }
  }

  if (lane == 0) {
    rv[wave * 3 + 0] = v0; ri[wave * 3 + 0] = i0;
    rv[wave * 3 + 1] = v1; ri[wave * 3 + 1] = i1;
    rv[wave * 3 + 2] = v2; ri[wave * 3 + 2] = i2;
  }
  __syncthreads();

  if (t == 0) {
#pragma unroll
    for (int w = 1; w < NW; ++w) {
      insert3_full(rv[w * 3 + 0], ri[w * 3 + 0], v0, i0, v1, i1, v2, i2);
      insert3_full(rv[w * 3 + 1], ri[w * 3 + 1], v0, i0, v1, i1, v2, i2);
      insert3_full(rv[w * 3 + 2], ri[w * 3 + 2], v0, i0, v1, i1, v2, i2);
    }

    float* __restrict__ nb = out;                      // neighbor_score
    float* __restrict__ ts = out + (size_t)rows * 3;   // topk_scores
    float* __restrict__ ti = out + (size_t)rows * 6;   // topk_index (as float)

    const int top = i0;
#pragma unroll
    for (int k = 0; k < 3; ++k) {
      int idx = top - 1 + k;
      idx = idx < 0 ? 0 : (idx > PW - 1 ? PW - 1 : idx);
      nb[row * 3 + k] = xr[idx];                       // L2-hot: row was just streamed
    }
    ts[row * 3 + 0] = v0;
    ts[row * 3 + 1] = v1;
    ts[row * 3 + 2] = v2;
    ti[row * 3 + 0] = (float)(i0 - PNLAG);
    ti[row * 3 + 1] = (float)(i1 - PNLAG);
    ti[row * 3 + 2] = (float)(i2 - PNLAG);
  }
}

extern "C" void kernel_launch(void* const* d_in, const int* in_sizes, int n_in,
                              void* d_out, int out_size, void* d_ws, size_t ws_size,
                              hipStream_t stream) {
  const float* x = (const float*)d_in[0];
  float* out = (float*)d_out;
  const int rows = in_sizes[0] / PW;   // 4096
  detect_peaks_kernel<<<rows, BLOCK, 0, stream>>>(x, out, rows);
}

// Round 2
// 240.517 us; speedup vs baseline: 1.0042x; 1.0042x over previous
//
#include <hip/hip_runtime.h>
#include <climits>
#include <cmath>

// DetectPeaks: xcorr [16,1,256,8192] f32 -> (neighbor_score, topk_scores, topk_index), each [rows,3]
// rows = 4096, W = 8192. One block (4 waves) per row, wave w owns elements [w*2048, w*2048+2048).
// Round-6 structure: batch-issue ALL 8 float4 loads per wave into a register array q[8]
// (8 KB in flight per wave -> HBM-latency covered by MLP, not occupancy), THEN a compute
// phase whose halo shuffles are all independent of in-flight loads. No LDS staging, no
// prefetch chain (round-5's per-iteration __shfl(nxt.x) serialized every load -> 1.16 TB/s).
// __launch_bounds__(256,4): 128-VGPR budget so q[] + accumulators fit with zero spill.

#define PW    8192
#define PNLAG (PW / 2)
#define BLOCK 256
#define NW    4                 // waves per block
#define J     8                 // float4 quads per lane: wave span = J*64*4 = 2048 elems

__device__ __forceinline__ bool better(float av, int ai, float bv, int bi) {
  return (av > bv) || ((av == bv) && (ai < bi));   // lax.top_k: ties -> lower index
}

__device__ __forceinline__ void insert3_full(float v, int i,
                                             float &v0, int &i0,
                                             float &v1, int &i1,
                                             float &v2, int &i2) {
  if (better(v, i, v2, i2)) {
    if (better(v, i, v1, i1)) {
      if (better(v, i, v0, i0)) {
        v2 = v1; i2 = i1; v1 = v0; i1 = i0; v0 = v; i0 = i;
      } else {
        v2 = v1; i2 = i1; v1 = v; i1 = i;
      }
    } else {
      v2 = v; i2 = i;
    }
  }
}

// Exact float ties between distinct lags have ~0 probability; strict > suffices.
__device__ __forceinline__ void insert3_fast(float c, int ci,
                                             float &v0, int &i0,
                                             float &v1, int &i1,
                                             float &v2, int &i2) {
  const bool b2 = c > v2;
  const bool b1 = c > v1;
  const bool b0 = c > v0;
  v2 = b1 ? v1 : (b2 ? c : v2);  i2 = b1 ? i1 : (b2 ? ci : i2);
  v1 = b0 ? v0 : (b1 ? c : v1);  i1 = b0 ? i0 : (b1 ? ci : i1);
  v0 = b0 ? c  : v0;             i0 = b0 ? ci : i0;
}

__global__ __launch_bounds__(BLOCK, 4)
void detect_peaks_kernel(const float* __restrict__ x,
                         float* __restrict__ out,
                         int rows) {
  __shared__ float rv[NW * 3];   // per-wave top-3 values
  __shared__ int   ri[NW * 3];   // per-wave top-3 indices

  const int row  = blockIdx.x;
  const int t    = threadIdx.x;
  const int lane = t & 63;
  const int wave = t >> 6;
  const float* __restrict__ xr = x + (size_t)row * PW;

  const int span = J * 64 * 4;          // 2048 elements per wave
  const int base = wave * span;

  // ---- load phase: all 8 coalesced float4 loads issued back-to-back (8 KB/wave in flight) ----
  float4 q[J];
#pragma unroll
  for (int j = 0; j < J; ++j)
    q[j] = *(const float4*)(xr + base + (j * 64 + lane) * 4);

  // Wave-edge halo elements (row edges pad -inf per torch max_pool2d semantics).
  // Wave-uniform addresses -> one cacheline request each; independent of q[] loads.
  const float edgeL = (base > 0)         ? xr[base - 1]    : -INFINITY;
  const float edgeR = (base + span < PW) ? xr[base + span] : -INFINITY;

  float v0 = -INFINITY, v1 = -INFINITY, v2 = -INFINITY;
  int   i0 = INT_MAX,   i1 = INT_MAX,   i2 = INT_MAX;

  // ---- compute phase: per-j fine-grained vmcnt waits; all shuffles load-independent ----
#pragma unroll
  for (int j = 0; j < J; ++j) {
    const float4 v = q[j];

    // left halo = element p-1: lane L>0 -> lane L-1's .w; lane 0 -> prev quad-row's lane63 .w
    float left = __shfl_up(v.w, 1);
    const float lf = (j == 0) ? edgeL : __shfl(q[j - 1].w, 63);
    if (lane == 0) left = lf;
    // right halo = element p+4: lane L<63 -> lane L+1's .x; lane 63 -> next quad-row's lane0 .x
    float right = __shfl_down(v.x, 1);
    const float rf = (j == J - 1) ? edgeR : __shfl(q[j + 1].x, 0);
    if (lane == 63) right = rf;

    const int p = base + (j * 64 + lane) * 4;   // first element index of this quad

    // sliding 3-max over the 4 positions
    const float p01 = fmaxf(v.x, v.y);
    const float p12 = fmaxf(v.y, v.z);
    const float p23 = fmaxf(v.z, v.w);
    const float m0 = fmaxf(left, p01);
    const float m1 = fmaxf(p01, v.z);
    const float m2 = fmaxf(p12, v.w);
    const float m3 = fmaxf(p23, right);

    // NMS score: x where local max else 0
    const float s0 = (v.x == m0) ? v.x : 0.0f;
    const float s1 = (v.y == m1) ? v.y : 0.0f;
    const float s2 = (v.z == m2) ? v.z : 0.0f;
    const float s3 = (v.w == m3) ? v.w : 0.0f;

    // quad top-2 (left arg of >= always lower index => tie->lower-index preserved);
    // adjacent lags can't both be (distinct-valued) local maxima -> <=2 survivors per quad.
    const bool  a01 = s0 >= s1;
    const float hiA = a01 ? s0 : s1;   const int hiAi = a01 ? p     : p + 1;
    const float loA = a01 ? s1 : s0;   const int loAi = a01 ? p + 1 : p;
    const bool  a23 = s2 >= s3;
    const float hiB = a23 ? s2 : s3;   const int hiBi = a23 ? p + 2 : p + 3;
    const float loB = a23 ? s3 : s2;   const int loBi = a23 ? p + 3 : p + 2;

    const bool  ab  = hiA >= hiB;
    const float c1  = ab ? hiA : hiB;  const int c1i = ab ? hiAi : hiBi;
    const bool  sb  = ab ? (loA >= hiB) : (hiA >= loB);
    const float c2  = ab ? (sb ? loA : hiB) : (sb ? hiA : loB);
    const int   c2i = ab ? (sb ? loAi : hiBi) : (sb ? hiAi : loBi);

    insert3_fast(c1, c1i, v0, i0, v1, i1, v2, i2);
    insert3_fast(c2, c2i, v0, i0, v1, i1, v2, i2);
  }

  // ---- wave-level tree merge (64 lanes) ----
#pragma unroll
  for (int off = 32; off > 0; off >>= 1) {
    float ov0 = __shfl_down(v0, off);
    int   oi0 = __shfl_down(i0, off);
    float ov1 = __shfl_down(v1, off);
    int   oi1 = __shfl_down(i1, off);
    float ov2 = __shfl_down(v2, off);
    int   oi2 = __shfl_down(i2, off);
    if (lane + off < 64) {
      insert3_full(ov0, oi0, v0, i0, v1, i1, v2, i2);
      insert3_full(ov1, oi1, v0, i0, v1, i1, v2, i2);
      insert3_full(ov2, oi2, v0, i0, v1, i1, v2, i2);
    }
  }

  if (lane == 0) {
    rv[wave * 3 + 0] = v0; ri[wave * 3 + 0] = i0;
    rv[wave * 3 + 1] = v1; ri[wave * 3 + 1] = i1;
    rv[wave * 3 + 2] = v2; ri[wave * 3 + 2] = i2;
  }
  __syncthreads();

  if (t == 0) {
#pragma unroll
    for (int w = 1; w < NW; ++w) {
      insert3_full(rv[w * 3 + 0], ri[w * 3 + 0], v0, i0, v1, i1, v2, i2);
      insert3_full(rv[w * 3 + 1], ri[w * 3 + 1], v0, i0, v1, i1, v2, i2);
      insert3_full(rv[w * 3 + 2], ri[w * 3 + 2], v0, i0, v1, i1, v2, i2);
    }

    float* __restrict__ nb = out;                      // neighbor_score
    float* __restrict__ ts = out + (size_t)rows * 3;   // topk_scores
    float* __restrict__ ti = out + (size_t)rows * 6;   // topk_index (as float)

    const int top = i0;
#pragma unroll
    for (int k = 0; k < 3; ++k) {
      int idx = top - 1 + k;
      idx = idx < 0 ? 0 : (idx > PW - 1 ? PW - 1 : idx);
      nb[row * 3 + k] = xr[idx];                       // L2-hot: row was just streamed
    }
    ts[row * 3 + 0] = v0;
    ts[row * 3 + 1] = v1;
    ts[row * 3 + 2] = v2;
    ti[row * 3 + 0] = (float)(i0 - PNLAG);
    ti[row * 3 + 1] = (float)(i1 - PNLAG);
    ti[row * 3 + 2] = (float)(i2 - PNLAG);
  }
}

extern "C" void kernel_launch(void* const* d_in, const int* in_sizes, int n_in,
                              void* d_out, int out_size, void* d_ws, size_t ws_size,
                              hipStream_t stream) {
  const float* x = (const float*)d_in[0];
  float* out = (float*)d_out;
  const int rows = in_sizes[0] / PW;   // 4096
  detect_peaks_kernel<<<rows, BLOCK, 0, stream>>>(x, out, rows);
}

// Round 3
// 239.412 us; speedup vs baseline: 1.0089x; 1.0046x over previous
//
#include <hip/hip_runtime.h>
#include <climits>
#include <cmath>

// DetectPeaks: xcorr [16,1,256,8192] f32 -> (neighbor_score, topk_scores, topk_index), each [rows,3]
// rows = 4096, W = 8192. One block (4 waves) per row, wave w owns elements [w*2048, w*2048+2048).
// Round-7 structure: round-6 intended "batch-issue all 8 float4 loads" but the compiler
// re-serialized them (VGPR_Count=28 < the 32 needed for q[8] alone -> loads sunk to uses,
// ~2-deep pipeline, 1.17 TB/s). This round PINS the load cluster with
// __builtin_amdgcn_sched_barrier(0): edge loads + all 8 dwordx4 loads issue before any
// compute can be hoisted above the fence, forcing 8 KB/wave in flight (true MLP).
// Experiment validity check: VGPR_Count must jump to ~64+.

#define PW    8192
#define PNLAG (PW / 2)
#define BLOCK 256
#define NW    4                 // waves per block
#define J     8                 // float4 quads per lane: wave span = J*64*4 = 2048 elems

__device__ __forceinline__ bool better(float av, int ai, float bv, int bi) {
  return (av > bv) || ((av == bv) && (ai < bi));   // lax.top_k: ties -> lower index
}

__device__ __forceinline__ void insert3_full(float v, int i,
                                             float &v0, int &i0,
                                             float &v1, int &i1,
                                             float &v2, int &i2) {
  if (better(v, i, v2, i2)) {
    if (better(v, i, v1, i1)) {
      if (better(v, i, v0, i0)) {
        v2 = v1; i2 = i1; v1 = v0; i1 = i0; v0 = v; i0 = i;
      } else {
        v2 = v1; i2 = i1; v1 = v; i1 = i;
      }
    } else {
      v2 = v; i2 = i;
    }
  }
}

// Exact float ties between distinct lags have ~0 probability; strict > suffices.
__device__ __forceinline__ void insert3_fast(float c, int ci,
                                             float &v0, int &i0,
                                             float &v1, int &i1,
                                             float &v2, int &i2) {
  const bool b2 = c > v2;
  const bool b1 = c > v1;
  const bool b0 = c > v0;
  v2 = b1 ? v1 : (b2 ? c : v2);  i2 = b1 ? i1 : (b2 ? ci : i2);
  v1 = b0 ? v0 : (b1 ? c : v1);  i1 = b0 ? i0 : (b1 ? ci : i1);
  v0 = b0 ? c  : v0;             i0 = b0 ? ci : i0;
}

__global__ __launch_bounds__(BLOCK, 4)
void detect_peaks_kernel(const float* __restrict__ x,
                         float* __restrict__ out,
                         int rows) {
  __shared__ float rv[NW * 3];   // per-wave top-3 values
  __shared__ int   ri[NW * 3];   // per-wave top-3 indices

  const int row  = blockIdx.x;
  const int t    = threadIdx.x;
  const int lane = t & 63;
  const int wave = t >> 6;
  const float* __restrict__ xr = x + (size_t)row * PW;

  const int span = J * 64 * 4;          // 2048 elements per wave
  const int base = wave * span;

  // ---- load phase: edge halos first, then all 8 coalesced float4 loads ----
  // Wave-edge halo elements (row edges pad -inf per torch max_pool2d semantics).
  const float edgeL = (base > 0)         ? xr[base - 1]    : -INFINITY;
  const float edgeR = (base + span < PW) ? xr[base + span] : -INFINITY;

  float4 q[J];
#pragma unroll
  for (int j = 0; j < J; ++j)
    q[j] = *(const float4*)(xr + base + (j * 64 + lane) * 4);

  // Fence: nothing moves across. All 10 VMEM loads are issued before any compute is
  // scheduled -> register allocator must keep q[0..7] live -> 8 KB/wave truly in flight.
  __builtin_amdgcn_sched_barrier(0);

  float v0 = -INFINITY, v1 = -INFINITY, v2 = -INFINITY;
  int   i0 = INT_MAX,   i1 = INT_MAX,   i2 = INT_MAX;

  // ---- compute phase: compiler emits fine-grained vmcnt(N) per q[j] use ----
#pragma unroll
  for (int j = 0; j < J; ++j) {
    const float4 v = q[j];

    // left halo = element p-1: lane L>0 -> lane L-1's .w; lane 0 -> prev quad-row's lane63 .w
    float left = __shfl_up(v.w, 1);
    const float lf = (j == 0) ? edgeL : __shfl(q[j - 1].w, 63);
    if (lane == 0) left = lf;
    // right halo = element p+4: lane L<63 -> lane L+1's .x; lane 63 -> next quad-row's lane0 .x
    float right = __shfl_down(v.x, 1);
    const float rf = (j == J - 1) ? edgeR : __shfl(q[j + 1].x, 0);
    if (lane == 63) right = rf;

    const int p = base + (j * 64 + lane) * 4;   // first element index of this quad

    // sliding 3-max over the 4 positions
    const float p01 = fmaxf(v.x, v.y);
    const float p12 = fmaxf(v.y, v.z);
    const float p23 = fmaxf(v.z, v.w);
    const float m0 = fmaxf(left, p01);
    const float m1 = fmaxf(p01, v.z);
    const float m2 = fmaxf(p12, v.w);
    const float m3 = fmaxf(p23, right);

    // NMS score: x where local max else 0
    const float s0 = (v.x == m0) ? v.x : 0.0f;
    const float s1 = (v.y == m1) ? v.y : 0.0f;
    const float s2 = (v.z == m2) ? v.z : 0.0f;
    const float s3 = (v.w == m3) ? v.w : 0.0f;

    // quad top-2 (left arg of >= always lower index => tie->lower-index preserved);
    // adjacent lags can't both be (distinct-valued) local maxima -> <=2 survivors per quad.
    const bool  a01 = s0 >= s1;
    const float hiA = a01 ? s0 : s1;   const int hiAi = a01 ? p     : p + 1;
    const float loA = a01 ? s1 : s0;   const int loAi = a01 ? p + 1 : p;
    const bool  a23 = s2 >= s3;
    const float hiB = a23 ? s2 : s3;   const int hiBi = a23 ? p + 2 : p + 3;
    const float loB = a23 ? s3 : s2;   const int loBi = a23 ? p + 3 : p + 2;

    const bool  ab  = hiA >= hiB;
    const float c1  = ab ? hiA : hiB;  const int c1i = ab ? hiAi : hiBi;
    const bool  sb  = ab ? (loA >= hiB) : (hiA >= loB);
    const float c2  = ab ? (sb ? loA : hiB) : (sb ? hiA : loB);
    const int   c2i = ab ? (sb ? loAi : hiBi) : (sb ? hiAi : loBi);

    insert3_fast(c1, c1i, v0, i0, v1, i1, v2, i2);
    insert3_fast(c2, c2i, v0, i0, v1, i1, v2, i2);
  }

  // ---- wave-level tree merge (64 lanes) ----
#pragma unroll
  for (int off = 32; off > 0; off >>= 1) {
    float ov0 = __shfl_down(v0, off);
    int   oi0 = __shfl_down(i0, off);
    float ov1 = __shfl_down(v1, off);
    int   oi1 = __shfl_down(i1, off);
    float ov2 = __shfl_down(v2, off);
    int   oi2 = __shfl_down(i2, off);
    if (lane + off < 64) {
      insert3_full(ov0, oi0, v0, i0, v1, i1, v2, i2);
      insert3_full(ov1, oi1, v0, i0, v1, i1, v2, i2);
      insert3_full(ov2, oi2, v0, i0, v1, i1, v2, i2);
    }
  }

  if (lane == 0) {
    rv[wave * 3 + 0] = v0; ri[wave * 3 + 0] = i0;
    rv[wave * 3 + 1] = v1; ri[wave * 3 + 1] = i1;
    rv[wave * 3 + 2] = v2; ri[wave * 3 + 2] = i2;
  }
  __syncthreads();

  if (t == 0) {
#pragma unroll
    for (int w = 1; w < NW; ++w) {
      insert3_full(rv[w * 3 + 0], ri[w * 3 + 0], v0, i0, v1, i1, v2, i2);
      insert3_full(rv[w * 3 + 1], ri[w * 3 + 1], v0, i0, v1, i1, v2, i2);
      insert3_full(rv[w * 3 + 2], ri[w * 3 + 2], v0, i0, v1, i1, v2, i2);
    }

    float* __restrict__ nb = out;                      // neighbor_score
    float* __restrict__ ts = out + (size_t)rows * 3;   // topk_scores
    float* __restrict__ ti = out + (size_t)rows * 6;   // topk_index (as float)

    const int top = i0;
#pragma unroll
    for (int k = 0; k < 3; ++k) {
      int idx = top - 1 + k;
      idx = idx < 0 ? 0 : (idx > PW - 1 ? PW - 1 : idx);
      nb[row * 3 + k] = xr[idx];                       // L2-hot: row was just streamed
    }
    ts[row * 3 + 0] = v0;
    ts[row * 3 + 1] = v1;
    ts[row * 3 + 2] = v2;
    ti[row * 3 + 0] = (float)(i0 - PNLAG);
    ti[row * 3 + 1] = (float)(i1 - PNLAG);
    ti[row * 3 + 2] = (float)(i2 - PNLAG);
  }
}

extern "C" void kernel_launch(void* const* d_in, const int* in_sizes, int n_in,
                              void* d_out, int out_size, void* d_ws, size_t ws_size,
                              hipStream_t stream) {
  const float* x = (const float*)d_in[0];
  float* out = (float*)d_out;
  const int rows = in_sizes[0] / PW;   // 4096
  detect_peaks_kernel<<<rows, BLOCK, 0, stream>>>(x, out, rows);
}